// Round 4
// baseline (1023.496 us; speedup 1.0000x reference)
//
#include <hip/hip_runtime.h>
#include <stdint.h>

#define NBATCH 512
#define NT     2048
#define NK     8
#define ND     32
#define PF     4   // prefetch ring depth == inner unroll

typedef float f2 __attribute__((ext_vector_type(2)));
typedef unsigned int u2 __attribute__((ext_vector_type(2)));

// Cross-half (lane ^ 32) sum. v_permlane32_swap_b32 with dst=src=x returns
// {row0 broadcast, row1 broadcast}, so r0+r1 = cross-half sum in every lane.
__device__ __forceinline__ float halfsum(float x) {
#if defined(__has_builtin) && __has_builtin(__builtin_amdgcn_permlane32_swap)
    u2 r = __builtin_amdgcn_permlane32_swap(__float_as_uint(x), __float_as_uint(x),
                                            false, false);
    return __uint_as_float(r.x) + __uint_as_float(r.y);
#else
    return x + __shfl_xor(x, 32);
#endif
}

// R4: 4 waves (256 thr) per batch element. wave w, lane (i=lane&31, kp=lane>>5)
// owns component k = w + 4*kp: ONE 32-float A row per lane (reg-resident,
// 16 f2 = 32 VGPR; R3's 128-float slice did not fit -> L1 reloads).
// Per-wave partial (2 k's) via permlane halfsum; cross-wave combine through a
// parity-double-buffered 2KB LDS tile + ONE __syncthreads per step.
// 512 blocks x 4 waves = 2048 waves = 2 waves/SIMD on all 1024 SIMDs (TLP
// finally hides FMA-chain + readlane latency; R3 had 1 wave on half the SIMDs).
__global__ __launch_bounds__(256, 1) void slds_kernel(
    const float* __restrict__ z0,
    const float* __restrict__ s_probs,
    const float* __restrict__ noise,
    const float* __restrict__ A_s,
    const float* __restrict__ b_s,
    const float* __restrict__ Q_chol,
    float* __restrict__ ys)
{
    const int b    = blockIdx.x;
    const int tid  = threadIdx.x;
    const int lane = tid & 63;
    const int w    = tid >> 6;        // wave id 0..3
    const int i    = lane & 31;
    const int kp   = lane >> 5;
    const int k    = w + 4 * kp;      // this lane's mixture component

    const float dt  = 0.05f;
    const float sdt = 0.22360679774997896f; // sqrt(0.05)

    __shared__ f2 red[2][4][ND];      // [parity][wave][i] = {acc, qacc} partials

    // ---- this lane's A row (32 f32 = 16 f2 regs), 16B loads ----
    f2 a2[16];
    {
        const float4* ap = (const float4*)(A_s + ((size_t)k * ND + i) * ND);
#pragma unroll
        for (int q = 0; q < 8; ++q) {
            float4 v = ap[q];
            a2[q * 2 + 0] = f2{v.x, v.y};
            a2[q * 2 + 1] = f2{v.z, v.w};
        }
    }
    const float breg = b_s[k * ND + i];
    const float qreg = Q_chol[k * ND + i];

    // ---- z: own element + broadcast via readlane ----
    float zi = z0[b * ND + i];
    f2 z2[16];
#pragma unroll
    for (int j = 0; j < 16; ++j) {
        z2[j].x = __int_as_float(__builtin_amdgcn_readlane(__float_as_int(zi), 2 * j));
        z2[j].y = __int_as_float(__builtin_amdgcn_readlane(__float_as_int(zi), 2 * j + 1));
    }

    const float4* wbase = (const float4*)s_probs;  // [T][B][2] float4
    const float*  nbase = noise;

    // ---- 4-deep prefetch ring (per lane: its kp-half float4 + its noise) ----
    float4 wv[PF];
    float  nr[PF];
#pragma unroll
    for (int u = 0; u < PF; ++u) {
        const size_t o = (size_t)u * (NBATCH * 2) + (size_t)b * 2 + kp;
        wv[u] = wbase[o];
        nr[u] = nbase[((size_t)u * NBATCH + b) * ND + i];
    }

    for (int t = 0; t < NT; t += PF) {
#pragma unroll
        for (int u = 0; u < PF; ++u) {
            const int tt = t + u;
            const int p  = tt & 1;            // LDS parity buffer
            const float4 wa  = wv[u];
            const float  nrc = nr[u];

            // prefetch step tt+PF into this slot (clamped; redundant tail ok)
            int tp = tt + PF; if (tp > NT - 1) tp = NT - 1;
            const size_t op = (size_t)tp * (NBATCH * 2) + (size_t)b * 2 + kp;
            wv[u] = wbase[op];
            nr[u] = nbase[((size_t)tp * NBATCH + b) * ND + i];

            // wsum from my half's float4 + cross-half swap (off dot path)
            float psum = (wa.x + wa.y) + (wa.z + wa.w);
            float wsum = halfsum(psum);
            float inv  = __builtin_amdgcn_rcpf(wsum);
            float g    = sdt * nrc;

            // my weight = component w of my half's float4 (w is wave-uniform)
            const float wk = (w == 0) ? wa.x : (w == 1) ? wa.y
                           : (w == 2) ? wa.z : wa.w;

            // y = b_k[i] + sum_j A[k][i][j] z[j]  (16-deep packed chain)
            f2 y01 = f2{breg, 0.f};
#pragma unroll
            for (int j = 0; j < 16; ++j)
                y01 = __builtin_elementwise_fma(a2[j], z2[j], y01);
            float pa = wk * (y01.x + y01.y);
            float pq = wk * qreg;

            // combine my wave's two k's (kp halves)
            pa = halfsum(pa);
            pq = halfsum(pq);

            // cross-wave combine: one LDS write + barrier + 4 reads
            if (lane < 32) red[p][w][i] = f2{pa, pq};
            __syncthreads();
            f2 s0 = red[p][0][i], s1 = red[p][1][i];
            f2 s2 = red[p][2][i], s3 = red[p][3][i];
            float acc  = (s0.x + s1.x) + (s2.x + s3.x);
            float qacc = (s0.y + s1.y) + (s2.y + s3.y);

            float znew = fmaf(inv, fmaf(dt, acc, g * qacc), zi);

            if (tid < 32) {
                const size_t oofs = ((size_t)tt * NBATCH + b) * ND + i;
                __builtin_nontemporal_store(znew, &ys[oofs]);  // streamed
            }

            // broadcast znew to all lanes' z2[] (every wave has it in lanes 0-31)
#pragma unroll
            for (int j = 0; j < 16; ++j) {
                z2[j].x = __int_as_float(__builtin_amdgcn_readlane(__float_as_int(znew), 2 * j));
                z2[j].y = __int_as_float(__builtin_amdgcn_readlane(__float_as_int(znew), 2 * j + 1));
            }
            zi = znew;
        }
    }
}

extern "C" void kernel_launch(void* const* d_in, const int* in_sizes, int n_in,
                              void* d_out, int out_size, void* d_ws, size_t ws_size,
                              hipStream_t stream) {
    const float* z0 = (const float*)d_in[0];
    const float* sp = (const float*)d_in[1];
    const float* no = (const float*)d_in[2];
    const float* As = (const float*)d_in[3];
    const float* bs = (const float*)d_in[4];
    const float* Qc = (const float*)d_in[5];
    float* ys = (float*)d_out;

    slds_kernel<<<dim3(NBATCH), dim3(256), 0, stream>>>(z0, sp, no, As, bs, Qc, ys);
}

// Round 5
// 934.721 us; speedup vs baseline: 1.0950x; 1.0950x over previous
//
#include <hip/hip_runtime.h>
#include <stdint.h>

#define NBATCH 512
#define NT     2048
#define NK     8
#define ND     32
#define PF     4   // prefetch ring depth == inner unroll

typedef float f2 __attribute__((ext_vector_type(2)));
typedef unsigned int u2 __attribute__((ext_vector_type(2)));

// Cross-half (lane ^ 32) sum. v_permlane32_swap_b32 with dst=src=x returns
// {row0 broadcast, row1 broadcast}, so r0+r1 = cross-half sum in every lane.
__device__ __forceinline__ float halfsum(float x) {
#if defined(__has_builtin) && __has_builtin(__builtin_amdgcn_permlane32_swap)
    u2 r = __builtin_amdgcn_permlane32_swap(__float_as_uint(x), __float_as_uint(x),
                                            false, false);
    return __uint_as_float(r.x) + __uint_as_float(r.y);
#else
    return x + __shfl_xor(x, 32);
#endif
}

// R5: back to 1 wave/block (R4's 4-wave k-split added barrier+LDS latency to
// the serial chain -> regression; wall time == per-chain latency x 2048).
//  - BLEND-FIRST: mrow = sum_kk w_kk * A_kk (z-INDEPENDENT, overlaps stalls),
//    then the z-dependent path is ONE 2x8-deep packed matvec (16 pk_fma)
//    instead of four 16-deep chains (64 pk_fma).
//  - A pinned in VGPRs via asm laundering: R3's VGPR_Count=92 proved the
//    compiler was rematerializing the 128-float A slice from L1 every step.
__global__ __launch_bounds__(64, 1) void slds_kernel(
    const float* __restrict__ z0,
    const float* __restrict__ s_probs,
    const float* __restrict__ noise,
    const float* __restrict__ A_s,
    const float* __restrict__ b_s,
    const float* __restrict__ Q_chol,
    float* __restrict__ ys)
{
    const int b    = blockIdx.x;
    const int lane = threadIdx.x;
    const int i    = lane & 31;
    const int kh   = lane >> 5;

    const float dt  = 0.05f;
    const float sdt = 0.22360679774997896f; // sqrt(0.05)

    // ---- A slice into registers as f2 pairs, 16B vector loads ----
    f2 a2[4][16];
#pragma unroll
    for (int kk = 0; kk < 4; ++kk) {
        const float4* ap = (const float4*)(A_s + (((size_t)(kh * 4 + kk) * ND + i) * ND));
#pragma unroll
        for (int q = 0; q < 8; ++q) {
            float4 v = ap[q];
            a2[kk][q * 2 + 0] = f2{v.x, v.y};
            a2[kk][q * 2 + 1] = f2{v.z, v.w};
        }
    }
    // Pin: launder through asm so the compiler cannot re-load A inside the
    // loop (forces true register residency; budget is 512 VGPR at 1 wave/EU).
#pragma unroll
    for (int kk = 0; kk < 4; ++kk)
#pragma unroll
        for (int j = 0; j < 16; ++j)
            asm volatile("" : "+v"(a2[kk][j]));

    float breg[4], qreg[4];
#pragma unroll
    for (int kk = 0; kk < 4; ++kk) {
        breg[kk] = b_s[(kh * 4 + kk) * ND + i];
        qreg[kk] = Q_chol[(kh * 4 + kk) * ND + i];
    }

    // ---- z: own element + broadcast via readlane (wave-uniform -> SGPRs) ----
    float zi = z0[b * ND + i];
    f2 z2[16];
#pragma unroll
    for (int j = 0; j < 16; ++j) {
        z2[j].x = __int_as_float(__builtin_amdgcn_readlane(__float_as_int(zi), 2 * j));
        z2[j].y = __int_as_float(__builtin_amdgcn_readlane(__float_as_int(zi), 2 * j + 1));
    }

    const float4* wbase = (const float4*)s_probs;  // [T][B][2] float4
    const float*  nbase = noise;

    // ---- 4-deep prefetch ring (my kh-half float4 + my noise element) ----
    float4 wv[PF];
    float  nr[PF];
#pragma unroll
    for (int u = 0; u < PF; ++u) {
        const size_t o = (size_t)u * (NBATCH * 2) + (size_t)b * 2 + kh;
        wv[u] = wbase[o];
        nr[u] = nbase[((size_t)u * NBATCH + b) * ND + i];
    }

    for (int t = 0; t < NT; t += PF) {
#pragma unroll
        for (int u = 0; u < PF; ++u) {
            const int tt = t + u;
            const float4 wa  = wv[u];
            const float  nrc = nr[u];

            // prefetch step tt+PF into this slot (clamped; redundant tail ok)
            int tp = tt + PF; if (tp > NT - 1) tp = NT - 1;
            const size_t op = (size_t)tp * (NBATCH * 2) + (size_t)b * 2 + kh;
            wv[u] = wbase[op];
            nr[u] = nbase[((size_t)tp * NBATCH + b) * ND + i];

            // ---- z-INDEPENDENT work (fills matvec-chain stalls) ----
            const float w0 = wa.x, w1 = wa.y, w2 = wa.z, w3 = wa.w;
            float psum = (w0 + w1) + (w2 + w3);
            float wsum = halfsum(psum);
            float inv  = __builtin_amdgcn_rcpf(wsum);
            float g    = sdt * nrc;

            // blend my half's 4 matrices into one row: m = sum_kk w_kk*A_kk[i][:]
            const f2 w0v = {w0, w0}, w1v = {w1, w1}, w2v = {w2, w2}, w3v = {w3, w3};
            f2 m[16];
#pragma unroll
            for (int j = 0; j < 16; ++j) {
                f2 mm = a2[0][j] * w0v;
                mm = __builtin_elementwise_fma(a2[1][j], w1v, mm);
                mm = __builtin_elementwise_fma(a2[2][j], w2v, mm);
                mm = __builtin_elementwise_fma(a2[3][j], w3v, mm);
                m[j] = mm;
            }
            float bb = (w0 * breg[0] + w1 * breg[1]) + (w2 * breg[2] + w3 * breg[3]);
            float qq = (w0 * qreg[0] + w1 * qreg[1]) + (w2 * qreg[2] + w3 * qreg[3]);
            float qacc = halfsum(qq);         // z-independent too

            // ---- z-DEPENDENT critical path: one 2x8-deep packed matvec ----
            f2 y0 = {bb, 0.f}, y1 = {0.f, 0.f};
#pragma unroll
            for (int j = 0; j < 8; ++j) {
                y0 = __builtin_elementwise_fma(m[j],     z2[j],     y0);
                y1 = __builtin_elementwise_fma(m[j + 8], z2[j + 8], y1);
            }
            f2 yt = y0 + y1;
            float acc = halfsum(yt.x + yt.y); // combine j-halves == k-halves blend

            float znew = fmaf(inv, fmaf(dt, acc, g * qacc), zi);

            if (lane < 32) {
                const size_t oofs = ((size_t)tt * NBATCH + b) * ND + i;
                __builtin_nontemporal_store(znew, &ys[oofs]);  // streamed
            }

            // broadcast znew to all lanes (readlane -> wave-uniform SGPRs)
#pragma unroll
            for (int j = 0; j < 16; ++j) {
                z2[j].x = __int_as_float(__builtin_amdgcn_readlane(__float_as_int(znew), 2 * j));
                z2[j].y = __int_as_float(__builtin_amdgcn_readlane(__float_as_int(znew), 2 * j + 1));
            }
            zi = znew;
        }
    }
}

extern "C" void kernel_launch(void* const* d_in, const int* in_sizes, int n_in,
                              void* d_out, int out_size, void* d_ws, size_t ws_size,
                              hipStream_t stream) {
    const float* z0 = (const float*)d_in[0];
    const float* sp = (const float*)d_in[1];
    const float* no = (const float*)d_in[2];
    const float* As = (const float*)d_in[3];
    const float* bs = (const float*)d_in[4];
    const float* Qc = (const float*)d_in[5];
    float* ys = (float*)d_out;

    slds_kernel<<<dim3(NBATCH), dim3(64), 0, stream>>>(z0, sp, no, As, bs, Qc, ys);
}